// Round 1
// baseline (1553.545 us; speedup 1.0000x reference)
//
#include <hip/hip_runtime.h>
#include <cmath>

// Problem constants
#define B_ 1024
#define V_ 8192
#define E_ 64
#define H_ 64
#define L_ 16
#define SOS 1
#define EOS 2

// d_out layout (floats), in reference return order:
// output [B,17,V] | seq_lengths [B] | entropy [1] | hidden_state [B,H] | embeds [B,L,E]
#define ONEHOT_OFF 0ull
#define SEQ_OFF    142606336ull
#define ENT_OFF    142607360ull
#define HID_OFF    142607361ull
#define EMB_OFF    142672897ull

// ---------------------------------------------------------------------------
// Kernel B: logits + online-softmax stats + argmax(l+g) partials.
// Grid: 512 = 64 row-groups (16 rows) x 8 v-splits (1024 v each).
// Each block: stage h[16x64] once; loop 4 chunks of 256 v: stage W_out chunk
// to LDS (coalesced), fp32 dot-64 per (row, v), online m/S/T + argmax.
// Wave = one row-group-of-4; lanes own strided v (tv, tv+64, tv+128, tv+192)
// so LDS reads have uniform bank coverage (row stride 68 => start bank
// 4*(lane%8), full 32-bank coverage).
// ---------------------------------------------------------------------------
__global__ __launch_bounds__(256, 2) void logits_stats_kernel(
    const float* __restrict__ Wout, const float* __restrict__ bout,
    const float* __restrict__ gstep,   // gumbels + step*B*V
    const float* __restrict__ h,       // ws: h after this step's LSTM cell
    float* __restrict__ pm, float* __restrict__ pS, float* __restrict__ pT,
    float* __restrict__ pbv, int* __restrict__ pbi)
{
    __shared__ float wV[256][68];   // W_out chunk, [v_local][k], pad 68
    __shared__ float hV[16][68];    // h rows, [r_local][k]

    const int t  = threadIdx.x;
    const int rg = blockIdx.x >> 3;   // row-group (vs = bx&7 -> one v-split per XCD)
    const int vs = blockIdx.x & 7;
    const int rowBase = rg * 16;
    const int tv = t & 63;            // lane
    const int tr = t >> 6;            // wave id = row-quad
    const int r0 = tr * 4;

    // stage h: 16 rows x 64, fully coalesced
    {
        const int rl = t >> 4;
        const int k0 = (t & 15) * 4;
        float4 hv = *(const float4*)(h + (size_t)(rowBase + rl) * 64 + k0);
        *(float4*)&hV[rl][k0] = hv;
    }

    float m[4], S[4], T[4], bv[4];
    int   bi[4];
#pragma unroll
    for (int r = 0; r < 4; ++r) {
        m[r] = -INFINITY; S[r] = 0.f; T[r] = 0.f; bv[r] = -INFINITY; bi[r] = 0;
    }

    for (int cc = 0; cc < 4; ++cc) {
        const int vglob = vs * 1024 + cc * 256;
        __syncthreads();   // previous chunk's compute done (also covers hV stage)
#pragma unroll
        for (int j = 0; j < 16; ++j) {           // stage 256x64 W_out chunk
            const int f  = (t + 256 * j) * 4;
            const int vl = f >> 6;
            const int k0 = f & 63;
            float4 w = *(const float4*)(Wout + (size_t)(vglob + vl) * 64 + k0);
            *(float4*)&wV[vl][k0] = w;
        }
        __syncthreads();

        float acc[4][4];
#pragma unroll
        for (int r = 0; r < 4; ++r)
#pragma unroll
            for (int j = 0; j < 4; ++j) acc[r][j] = 0.f;

#pragma unroll 4
        for (int k4 = 0; k4 < 16; ++k4) {
            float4 wv[4], hv[4];
#pragma unroll
            for (int j = 0; j < 4; ++j) wv[j] = *(const float4*)&wV[tv + 64 * j][k4 * 4];
#pragma unroll
            for (int r = 0; r < 4; ++r) hv[r] = *(const float4*)&hV[r0 + r][k4 * 4];
#pragma unroll
            for (int r = 0; r < 4; ++r)
#pragma unroll
                for (int j = 0; j < 4; ++j)
                    acc[r][j] += hv[r].x * wv[j].x + hv[r].y * wv[j].y +
                                 hv[r].z * wv[j].z + hv[r].w * wv[j].w;
        }

        // epilogue: logits -> online stats + argmax(l+g). v ascending in j.
#pragma unroll
        for (int j = 0; j < 4; ++j) {
            const int v  = vglob + 64 * j + tv;
            const float bo = bout[v];
#pragma unroll
            for (int r = 0; r < 4; ++r) {
                const int row = rowBase + r0 + r;
                const float l = acc[r][j] + bo;
                const float s = l + gstep[(size_t)row * V_ + v];
                if (s > bv[r]) { bv[r] = s; bi[r] = v; }   // strict > keeps lowest v
                const float mn = fmaxf(m[r], l);
                const float e  = __expf(-fabsf(l - m[r])); // exp(-inf)=0 first time
                const bool nw  = l > m[r];
                const float a  = nw ? e : 1.f;
                const float b2 = nw ? 1.f : e;
                S[r] = S[r] * a + b2;
                T[r] = T[r] * a + l * b2;
                m[r] = mn;
            }
        }
    }

    // wave-64 butterfly reduction across lanes (each wave = 4 rows)
#pragma unroll
    for (int off = 1; off < 64; off <<= 1) {
#pragma unroll
        for (int r = 0; r < 4; ++r) {
            const float mo  = __shfl_xor(m[r], off);
            const float So  = __shfl_xor(S[r], off);
            const float To  = __shfl_xor(T[r], off);
            const float bvo = __shfl_xor(bv[r], off);
            const int   bio = __shfl_xor(bi[r], off);
            const float mn = fmaxf(m[r], mo);
            const float ea = __expf(m[r] - mn);
            const float eb = __expf(mo - mn);
            S[r] = S[r] * ea + So * eb;
            T[r] = T[r] * ea + To * eb;
            m[r] = mn;
            if (bvo > bv[r] || (bvo == bv[r] && bio < bi[r])) { bv[r] = bvo; bi[r] = bio; }
        }
    }
    if (tv == 0) {
#pragma unroll
        for (int r = 0; r < 4; ++r) {
            const int row = rowBase + r0 + r;
            const int o = vs * 1024 + row;
            pm[o] = m[r]; pS[o] = S[r]; pT[o] = T[r]; pbv[o] = bv[r]; pbi[o] = bi[r];
        }
    }
}

// ---------------------------------------------------------------------------
// Kernel C: combine per-split stats -> token / one-hot / entropy / seq_len,
// then run the NEXT step's LSTM cell (emb gather, gates GEMM, c/h update).
// step = -1: no combine; LSTM step 0 from SOS token, h = hidden_in, c = 0.
// step = 15: combine + finalize (seq floats, entropy atomicAdd), no LSTM.
// Grid: 128 blocks x 256 threads, 8 rows per block.
// ---------------------------------------------------------------------------
__global__ __launch_bounds__(256) void combine_lstm_kernel(
    const float* __restrict__ emb_table,
    const float* __restrict__ W_ih, const float* __restrict__ W_hh,
    const float* __restrict__ b_ih, const float* __restrict__ b_hh,
    const float* __restrict__ hidden_in,
    float* __restrict__ h, float* __restrict__ c,
    float* __restrict__ ent, int* __restrict__ seq,
    const float* __restrict__ pm, const float* __restrict__ pS,
    const float* __restrict__ pT, const float* __restrict__ pbv,
    const int* __restrict__ pbi,
    float* __restrict__ out, int step)
{
    __shared__ float wrow[256][132];  // [gate j][k], k<64: W_ih, k>=64: W_hh
    __shared__ float xcat[8][128];    // [row][emb(64) | h(64)]
    __shared__ float gatesL[8][256];
    __shared__ int   toksL[8];
    __shared__ float entL[8];

    const int t = threadIdx.x;
    const int rowBase = blockIdx.x * 8;

    if (step >= 0) {
        if (t < 8) {
            const int row = rowBase + t;
            float m = -INFINITY, S = 0.f, T = 0.f, bv = -INFINITY; int bi = 0;
            for (int s = 0; s < 8; ++s) {   // ascending split = ascending v
                const int o = s * 1024 + row;
                const float ms = pm[o], Ss = pS[o], Ts = pT[o], bvs = pbv[o];
                const int bis = pbi[o];
                const float mn = fmaxf(m, ms);
                const float ea = __expf(m - mn), eb = __expf(ms - mn);
                S = S * ea + Ss * eb; T = T * ea + Ts * eb; m = mn;
                if (bvs > bv || (bvs == bv && bis < bi)) { bv = bvs; bi = bis; }
            }
            const float lse  = m + logf(S);
            const float entc = lse - T / S;
            const int tok = bi;
            out[ONEHOT_OFF + (size_t)row * (17 * 8192) + (size_t)(step + 1) * 8192 + tok] = 1.0f;
            const float ev = (step == 0) ? entc : (ent[row] + entc);
            ent[row] = ev;
            int sl = (step == 0) ? (L_ + 1) : seq[row];
            if (tok == EOS && sl == (L_ + 1)) sl = step + 2;  // (max_pred==1.0 always)
            seq[row] = sl;
            toksL[t] = tok;
            entL[t] = ev;
            if (step == 15) out[SEQ_OFF + row] = (float)sl;
        }
    } else {
        if (t < 8) {
            const int row = rowBase + t;
            toksL[t] = SOS;
            out[ONEHOT_OFF + (size_t)row * (17 * 8192) + SOS] = 1.0f;  // t=0 SOS one-hot
        }
    }
    __syncthreads();

    if (step == 15) {
        if (t == 0) {
            float a = 0.f;
            for (int r = 0; r < 8; ++r) a += entL[r];
            atomicAdd(out + ENT_OFF, a * (1.0f / (1024.0f * 16.0f)));
        }
        return;
    }

    // stage W_ih|W_hh as [j][0:128]
#pragma unroll
    for (int j = 0; j < 16; ++j) {
        const int f  = (t + 256 * j) * 4;   // 0..16383
        const int gr = f >> 6;
        const int k0 = f & 63;
        *(float4*)&wrow[gr][k0]      = *(const float4*)(W_ih + f);
        *(float4*)&wrow[gr][64 + k0] = *(const float4*)(W_hh + f);
    }
    // stage x = [emb(tok) | h_prev]; also write embeds output
    if (t < 128) {
        const int r = t >> 4, k0 = (t & 15) * 4;
        const int row = rowBase + r;
        const int tk = (step < 0) ? SOS : toksL[r];
        float4 evv = *(const float4*)(emb_table + (size_t)tk * 64 + k0);
        *(float4*)&xcat[r][k0] = evv;
        const size_t eo = EMB_OFF + ((size_t)row * 16 + (size_t)(step + 1)) * 64 + k0;
        out[eo + 0] = evv.x; out[eo + 1] = evv.y; out[eo + 2] = evv.z; out[eo + 3] = evv.w;
    } else {
        const int tt = t - 128;
        const int r = tt >> 4, k0 = (tt & 15) * 4;
        const int row = rowBase + r;
        const float* hsrc = (step < 0) ? (hidden_in + (size_t)row * 64 + k0)
                                       : (h + (size_t)row * 64 + k0);
        float4 hv = *(const float4*)hsrc;
        *(float4*)&xcat[r][64 + k0] = hv;
    }
    __syncthreads();

    // gates: thread t = gate j, 8 rows each, K=128
    {
        const float bia = b_ih[t] + b_hh[t];
        float acc[8];
#pragma unroll
        for (int r = 0; r < 8; ++r) acc[r] = bia;
        for (int k4 = 0; k4 < 32; ++k4) {
            const float4 w4 = *(const float4*)&wrow[t][k4 * 4];
#pragma unroll
            for (int r = 0; r < 8; ++r) {
                const float4 x4 = *(const float4*)&xcat[r][k4 * 4];
                acc[r] += x4.x * w4.x + x4.y * w4.y + x4.z * w4.z + x4.w * w4.w;
            }
        }
#pragma unroll
        for (int r = 0; r < 8; ++r) gatesL[r][t] = acc[r];
    }
    __syncthreads();

    // LSTM cell: 512 units, 2 per thread (torch gate order i,f,g,o)
#pragma unroll
    for (int q = 0; q < 2; ++q) {
        const int u = t + q * 256;
        const int r = u >> 6, uu = u & 63;
        const int row = rowBase + r;
        const float ii = gatesL[r][uu];
        const float ff = gatesL[r][64 + uu];
        const float gg = gatesL[r][128 + uu];
        const float oo = gatesL[r][192 + uu];
        const float cp = (step < 0) ? 0.f : c[(size_t)row * 64 + uu];
        const float si = 1.f / (1.f + expf(-ii));
        const float sf = 1.f / (1.f + expf(-ff));
        const float so = 1.f / (1.f + expf(-oo));
        const float cn = sf * cp + si * tanhf(gg);
        const float hn = so * tanhf(cn);
        c[(size_t)row * 64 + uu] = cn;
        h[(size_t)row * 64 + uu] = hn;
    }
}

extern "C" void kernel_launch(void* const* d_in, const int* in_sizes, int n_in,
                              void* d_out, int out_size, void* d_ws, size_t ws_size,
                              hipStream_t stream) {
    (void)in_sizes; (void)ws_size;
    if (n_in < 9) return;
    const float* hidden    = (const float*)d_in[0];
    const float* embedding = (const float*)d_in[1];
    const float* W_ih      = (const float*)d_in[2];
    const float* W_hh      = (const float*)d_in[3];
    const float* b_ih      = (const float*)d_in[4];
    const float* b_hh      = (const float*)d_in[5];
    const float* W_out     = (const float*)d_in[6];
    const float* b_out     = (const float*)d_in[7];
    const float* gumbels   = (const float*)d_in[8];
    float* out = (float*)d_out;

    // workspace: h[64K] c[64K] ent[1K] seq[1K] pm/pS/pT/pbv/pbi[8x1024 each]
    float* wsf = (float*)d_ws;
    float* h   = wsf;
    float* c   = wsf + 65536;
    float* ent = wsf + 131072;
    int*   seq = (int*)(wsf + 132096);
    float* pm  = wsf + 133120;
    float* pS  = pm + 8192;
    float* pT  = pS + 8192;
    float* pbv = pT + 8192;
    int*   pbi = (int*)(pbv + 8192);

    hipMemsetAsync(d_out, 0, (size_t)out_size * sizeof(float), stream);
    hipMemcpyAsync(out + HID_OFF, hidden, (size_t)B_ * H_ * sizeof(float),
                   hipMemcpyDeviceToDevice, stream);

    // step -1: LSTM cell 0 (SOS embed, h0 = input, c0 = 0) + SOS one-hot + embeds[:,0]
    combine_lstm_kernel<<<128, 256, 0, stream>>>(embedding, W_ih, W_hh, b_ih, b_hh,
        hidden, h, c, ent, seq, pm, pS, pT, pbv, pbi, out, -1);
    for (int i = 0; i < 16; ++i) {
        logits_stats_kernel<<<512, 256, 0, stream>>>(W_out, b_out,
            gumbels + (size_t)i * B_ * V_, h, pm, pS, pT, pbv, pbi);
        combine_lstm_kernel<<<128, 256, 0, stream>>>(embedding, W_ih, W_hh, b_ih, b_hh,
            hidden, h, c, ent, seq, pm, pS, pT, pbv, pbi, out, i);
    }
}

// Round 3
// 1530.222 us; speedup vs baseline: 1.0152x; 1.0152x over previous
//
#include <hip/hip_runtime.h>
#include <cmath>

// Problem constants
#define B_ 1024
#define V_ 8192
#define E_ 64
#define H_ 64
#define L_ 16
#define SOS 1
#define EOS 2

typedef float f32x4 __attribute__((ext_vector_type(4)));

// d_out layout (floats), in reference return order:
// output [B,17,V] | seq_lengths [B] | entropy [1] | hidden_state [B,H] | embeds [B,L,E]
#define ONEHOT_OFF 0ull
#define SEQ_OFF    142606336ull
#define ENT_OFF    142607360ull
#define HID_OFF    142607361ull
#define EMB_OFF    142672897ull

// ---------------------------------------------------------------------------
// Init kernel: zero one-hot slab 0 (all rows) + write SOS one-hot + ent=0.
// Grid: 1024 blocks (one row each) x 256 threads.
// ---------------------------------------------------------------------------
__global__ __launch_bounds__(256) void init_zero_kernel(float* __restrict__ out)
{
    const int t = threadIdx.x;
    const int row = blockIdx.x;
    float* slab = out + ONEHOT_OFF + (size_t)row * (17 * 8192);  // slot 0
#pragma unroll
    for (int j = 0; j < 8; ++j) {
        f32x4 z = {0.f, 0.f, 0.f, 0.f};
        if (j == 0 && t == 0) z.y = 1.0f;   // v=1 == SOS
        __builtin_nontemporal_store(z, (f32x4*)(slab + j * 1024 + t * 4));
    }
    if (row == 0 && t == 1) out[ENT_OFF] = 0.f;
}

// ---------------------------------------------------------------------------
// Kernel B: logits + online-softmax stats + argmax(l+g) partials.
// Also zeroes the one-hot slab for slot step+1 (fused zero-fill replacing
// the 365us runtime memset; nontemporal so it doesn't evict W_out from L2).
// Grid: 512 = 64 row-groups (16 rows) x 8 v-splits (1024 v each).
// ---------------------------------------------------------------------------
__global__ __launch_bounds__(256, 2) void logits_stats_kernel(
    const float* __restrict__ Wout, const float* __restrict__ bout,
    const float* __restrict__ gstep,   // gumbels + step*B*V
    const float* __restrict__ h,       // ws: h after this step's LSTM cell
    float* __restrict__ pm, float* __restrict__ pS, float* __restrict__ pT,
    float* __restrict__ pbv, int* __restrict__ pbi,
    float* __restrict__ out, int step)
{
    __shared__ float wV[256][68];   // W_out chunk, [v_local][k], pad 68
    __shared__ float hV[16][68];    // h rows, [r_local][k]

    const int t  = threadIdx.x;
    const int rg = blockIdx.x >> 3;   // row-group (vs = bx&7 -> one v-split per XCD)
    const int vs = blockIdx.x & 7;
    const int rowBase = rg * 16;
    const int tv = t & 63;            // lane
    const int tr = t >> 6;            // wave id = row-quad
    const int r0 = tr * 4;

    // stage h: 16 rows x 64, fully coalesced
    {
        const int rl = t >> 4;
        const int k0 = (t & 15) * 4;
        float4 hv = *(const float4*)(h + (size_t)(rowBase + rl) * 64 + k0);
        *(float4*)&hV[rl][k0] = hv;
    }

    // fused zero-fill of one-hot slab (step+1), this block's 16 rows x 1024 v
    {
        const f32x4 z = {0.f, 0.f, 0.f, 0.f};
        const size_t slab = ONEHOT_OFF + (size_t)(step + 1) * 8192 + (size_t)(vs * 1024 + t * 4);
#pragma unroll
        for (int r = 0; r < 16; ++r) {
            __builtin_nontemporal_store(z,
                (f32x4*)(out + (size_t)(rowBase + r) * (17 * 8192) + slab));
        }
    }

    float m[4], S[4], T[4], bv[4];
    int   bi[4];
#pragma unroll
    for (int r = 0; r < 4; ++r) {
        m[r] = -INFINITY; S[r] = 0.f; T[r] = 0.f; bv[r] = -INFINITY; bi[r] = 0;
    }

    for (int cc = 0; cc < 4; ++cc) {
        const int vglob = vs * 1024 + cc * 256;
        __syncthreads();   // previous chunk's compute done (also covers hV stage)
#pragma unroll
        for (int j = 0; j < 16; ++j) {           // stage 256x64 W_out chunk
            const int f  = (t + 256 * j) * 4;
            const int vl = f >> 6;
            const int k0 = f & 63;
            float4 w = *(const float4*)(Wout + (size_t)(vglob + vl) * 64 + k0);
            *(float4*)&wV[vl][k0] = w;
        }
        __syncthreads();

        float acc[4][4];
#pragma unroll
        for (int r = 0; r < 4; ++r)
#pragma unroll
            for (int j = 0; j < 4; ++j) acc[r][j] = 0.f;

#pragma unroll 4
        for (int k4 = 0; k4 < 16; ++k4) {
            float4 wv[4], hv[4];
#pragma unroll
            for (int j = 0; j < 4; ++j) wv[j] = *(const float4*)&wV[tv + 64 * j][k4 * 4];
#pragma unroll
            for (int r = 0; r < 4; ++r) hv[r] = *(const float4*)&hV[r0 + r][k4 * 4];
#pragma unroll
            for (int r = 0; r < 4; ++r)
#pragma unroll
                for (int j = 0; j < 4; ++j)
                    acc[r][j] += hv[r].x * wv[j].x + hv[r].y * wv[j].y +
                                 hv[r].z * wv[j].z + hv[r].w * wv[j].w;
        }

        // epilogue: logits -> online stats + argmax(l+g). v ascending in j.
#pragma unroll
        for (int j = 0; j < 4; ++j) {
            const int v  = vglob + 64 * j + tv;
            const float bo = bout[v];
#pragma unroll
            for (int r = 0; r < 4; ++r) {
                const int row = rowBase + r0 + r;
                const float l = acc[r][j] + bo;
                const float s = l + gstep[(size_t)row * V_ + v];
                if (s > bv[r]) { bv[r] = s; bi[r] = v; }   // strict > keeps lowest v
                const float mn = fmaxf(m[r], l);
                const float e  = __expf(-fabsf(l - m[r])); // exp(-inf)=0 first time
                const bool nw  = l > m[r];
                const float a  = nw ? e : 1.f;
                const float b2 = nw ? 1.f : e;
                S[r] = S[r] * a + b2;
                T[r] = T[r] * a + l * b2;
                m[r] = mn;
            }
        }
    }

    // wave-64 butterfly reduction across lanes (each wave = 4 rows)
#pragma unroll
    for (int off = 1; off < 64; off <<= 1) {
#pragma unroll
        for (int r = 0; r < 4; ++r) {
            const float mo  = __shfl_xor(m[r], off);
            const float So  = __shfl_xor(S[r], off);
            const float To  = __shfl_xor(T[r], off);
            const float bvo = __shfl_xor(bv[r], off);
            const int   bio = __shfl_xor(bi[r], off);
            const float mn = fmaxf(m[r], mo);
            const float ea = __expf(m[r] - mn);
            const float eb = __expf(mo - mn);
            S[r] = S[r] * ea + So * eb;
            T[r] = T[r] * ea + To * eb;
            m[r] = mn;
            if (bvo > bv[r] || (bvo == bv[r] && bio < bi[r])) { bv[r] = bvo; bi[r] = bio; }
        }
    }
    if (tv == 0) {
#pragma unroll
        for (int r = 0; r < 4; ++r) {
            const int row = rowBase + r0 + r;
            const int o = vs * 1024 + row;
            pm[o] = m[r]; pS[o] = S[r]; pT[o] = T[r]; pbv[o] = bv[r]; pbi[o] = bi[r];
        }
    }
}

// ---------------------------------------------------------------------------
// Kernel C: combine per-split stats -> token / one-hot / entropy / seq_len,
// then run the NEXT step's LSTM cell (emb gather, gates GEMM, c/h update).
// step = -1: no combine; LSTM step 0 from SOS token, h = hidden_in, c = 0.
// step = 15: combine + finalize (seq floats, entropy atomicAdd), no LSTM.
// Grid: 128 blocks x 256 threads, 8 rows per block.
// ---------------------------------------------------------------------------
__global__ __launch_bounds__(256) void combine_lstm_kernel(
    const float* __restrict__ emb_table,
    const float* __restrict__ W_ih, const float* __restrict__ W_hh,
    const float* __restrict__ b_ih, const float* __restrict__ b_hh,
    const float* __restrict__ hidden_in,
    float* __restrict__ h, float* __restrict__ c,
    float* __restrict__ ent, int* __restrict__ seq,
    const float* __restrict__ pm, const float* __restrict__ pS,
    const float* __restrict__ pT, const float* __restrict__ pbv,
    const int* __restrict__ pbi,
    float* __restrict__ out, int step)
{
    __shared__ float wrow[256][132];  // [gate j][k], k<64: W_ih, k>=64: W_hh
    __shared__ float xcat[8][128];    // [row][emb(64) | h(64)]
    __shared__ float gatesL[8][256];
    __shared__ int   toksL[8];
    __shared__ float entL[8];

    const int t = threadIdx.x;
    const int rowBase = blockIdx.x * 8;

    if (step >= 0) {
        if (t < 8) {
            const int row = rowBase + t;
            float m = -INFINITY, S = 0.f, T = 0.f, bv = -INFINITY; int bi = 0;
            for (int s = 0; s < 8; ++s) {   // ascending split = ascending v
                const int o = s * 1024 + row;
                const float ms = pm[o], Ss = pS[o], Ts = pT[o], bvs = pbv[o];
                const int bis = pbi[o];
                const float mn = fmaxf(m, ms);
                const float ea = __expf(m - mn), eb = __expf(ms - mn);
                S = S * ea + Ss * eb; T = T * ea + Ts * eb; m = mn;
                if (bvs > bv || (bvs == bv && bis < bi)) { bv = bvs; bi = bis; }
            }
            const float lse  = m + logf(S);
            const float entc = lse - T / S;
            const int tok = bi;
            out[ONEHOT_OFF + (size_t)row * (17 * 8192) + (size_t)(step + 1) * 8192 + tok] = 1.0f;
            const float ev = (step == 0) ? entc : (ent[row] + entc);
            ent[row] = ev;
            int sl = (step == 0) ? (L_ + 1) : seq[row];
            if (tok == EOS && sl == (L_ + 1)) sl = step + 2;  // (max_pred==1.0 always)
            seq[row] = sl;
            toksL[t] = tok;
            entL[t] = ev;
            if (step == 15) out[SEQ_OFF + row] = (float)sl;
        }
    } else {
        if (t < 8) toksL[t] = SOS;   // SOS one-hot written by init kernel
    }
    __syncthreads();

    if (step == 15) {
        if (t == 0) {
            float a = 0.f;
            for (int r = 0; r < 8; ++r) a += entL[r];
            atomicAdd(out + ENT_OFF, a * (1.0f / (1024.0f * 16.0f)));
        }
        return;
    }

    // stage W_ih|W_hh as [j][0:128]
#pragma unroll
    for (int j = 0; j < 16; ++j) {
        const int f  = (t + 256 * j) * 4;   // 0..16383
        const int gr = f >> 6;
        const int k0 = f & 63;
        *(float4*)&wrow[gr][k0]      = *(const float4*)(W_ih + f);
        *(float4*)&wrow[gr][64 + k0] = *(const float4*)(W_hh + f);
    }
    // stage x = [emb(tok) | h_prev]; also write embeds output
    if (t < 128) {
        const int r = t >> 4, k0 = (t & 15) * 4;
        const int row = rowBase + r;
        const int tk = (step < 0) ? SOS : toksL[r];
        float4 evv = *(const float4*)(emb_table + (size_t)tk * 64 + k0);
        *(float4*)&xcat[r][k0] = evv;
        const size_t eo = EMB_OFF + ((size_t)row * 16 + (size_t)(step + 1)) * 64 + k0;
        out[eo + 0] = evv.x; out[eo + 1] = evv.y; out[eo + 2] = evv.z; out[eo + 3] = evv.w;
    } else {
        const int tt = t - 128;
        const int r = tt >> 4, k0 = (tt & 15) * 4;
        const int row = rowBase + r;
        const float* hsrc = (step < 0) ? (hidden_in + (size_t)row * 64 + k0)
                                       : (h + (size_t)row * 64 + k0);
        float4 hv = *(const float4*)hsrc;
        *(float4*)&xcat[r][64 + k0] = hv;
    }
    __syncthreads();

    // gates: thread t = gate j, 8 rows each, K=128
    {
        const float bia = b_ih[t] + b_hh[t];
        float acc[8];
#pragma unroll
        for (int r = 0; r < 8; ++r) acc[r] = bia;
        for (int k4 = 0; k4 < 32; ++k4) {
            const float4 w4 = *(const float4*)&wrow[t][k4 * 4];
#pragma unroll
            for (int r = 0; r < 8; ++r) {
                const float4 x4 = *(const float4*)&xcat[r][k4 * 4];
                acc[r] += x4.x * w4.x + x4.y * w4.y + x4.z * w4.z + x4.w * w4.w;
            }
        }
#pragma unroll
        for (int r = 0; r < 8; ++r) gatesL[r][t] = acc[r];
    }
    __syncthreads();

    // LSTM cell: 512 units, 2 per thread (torch gate order i,f,g,o)
#pragma unroll
    for (int q = 0; q < 2; ++q) {
        const int u = t + q * 256;
        const int r = u >> 6, uu = u & 63;
        const int row = rowBase + r;
        const float ii = gatesL[r][uu];
        const float ff = gatesL[r][64 + uu];
        const float gg = gatesL[r][128 + uu];
        const float oo = gatesL[r][192 + uu];
        const float cp = (step < 0) ? 0.f : c[(size_t)row * 64 + uu];
        const float si = 1.f / (1.f + expf(-ii));
        const float sf = 1.f / (1.f + expf(-ff));
        const float so = 1.f / (1.f + expf(-oo));
        const float cn = sf * cp + si * tanhf(gg);
        const float hn = so * tanhf(cn);
        c[(size_t)row * 64 + uu] = cn;
        h[(size_t)row * 64 + uu] = hn;
    }
}

extern "C" void kernel_launch(void* const* d_in, const int* in_sizes, int n_in,
                              void* d_out, int out_size, void* d_ws, size_t ws_size,
                              hipStream_t stream) {
    (void)in_sizes; (void)ws_size; (void)out_size;
    if (n_in < 9) return;
    const float* hidden    = (const float*)d_in[0];
    const float* embedding = (const float*)d_in[1];
    const float* W_ih      = (const float*)d_in[2];
    const float* W_hh      = (const float*)d_in[3];
    const float* b_ih      = (const float*)d_in[4];
    const float* b_hh      = (const float*)d_in[5];
    const float* W_out     = (const float*)d_in[6];
    const float* b_out     = (const float*)d_in[7];
    const float* gumbels   = (const float*)d_in[8];
    float* out = (float*)d_out;

    // workspace: h[64K] c[64K] ent[1K] seq[1K] pm/pS/pT/pbv/pbi[8x1024 each]
    float* wsf = (float*)d_ws;
    float* h   = wsf;
    float* c   = wsf + 65536;
    float* ent = wsf + 131072;
    int*   seq = (int*)(wsf + 132096);
    float* pm  = wsf + 133120;
    float* pS  = pm + 8192;
    float* pT  = pS + 8192;
    float* pbv = pT + 8192;
    int*   pbi = (int*)(pbv + 8192);

    (void)hipMemcpyAsync(out + HID_OFF, hidden, (size_t)B_ * H_ * sizeof(float),
                         hipMemcpyDeviceToDevice, stream);
    init_zero_kernel<<<1024, 256, 0, stream>>>(out);

    // step -1: LSTM cell 0 (SOS embed, h0 = input, c0 = 0) + embeds[:,0]
    combine_lstm_kernel<<<128, 256, 0, stream>>>(embedding, W_ih, W_hh, b_ih, b_hh,
        hidden, h, c, ent, seq, pm, pS, pT, pbv, pbi, out, -1);
    for (int i = 0; i < 16; ++i) {
        logits_stats_kernel<<<512, 256, 0, stream>>>(W_out, b_out,
            gumbels + (size_t)i * B_ * V_, h, pm, pS, pT, pbv, pbi, out, i);
        combine_lstm_kernel<<<128, 256, 0, stream>>>(embedding, W_ih, W_hh, b_ih, b_hh,
            hidden, h, c, ent, seq, pm, pS, pT, pbv, pbi, out, i);
    }
}